// Round 22
// baseline (79.260 us; speedup 1.0000x reference)
//
#include <hip/hip_runtime.h>

typedef __bf16 bf16x8_t __attribute__((ext_vector_type(8)));
typedef float  f32x4_t  __attribute__((ext_vector_type(4)));
typedef int    i32x4_t  __attribute__((ext_vector_type(4)));

#define EDGES 28
#define TIN   4096
#define T2V   8192
#define NB    16
#define CIN   224
#define COUT  448
#define MT    512
#define ROWS  514

__device__ __forceinline__ unsigned short f2bf(float f) {
    unsigned int u = __builtin_bit_cast(unsigned int, f);
    u = (u + 0x7fffu + ((u >> 16) & 1u)) >> 16;   // RNE
    return (unsigned short)u;
}
__device__ __forceinline__ float bf2f(unsigned short h) {
    unsigned int u = ((unsigned int)h) << 16;
    return __builtin_bit_cast(float, u);
}

// LDS layout: [mr][ch] rows of 128 B (48 ch used of 64), XOR-swizzled 16B slots.
__device__ __forceinline__ int lds_byte(int mr, int ch) {
    return (mr << 7) + ((((ch >> 3) ^ (mr & 7))) << 4) + ((ch & 7) << 1);
}

// ---------------------------------------------------------------------------
// Prep: fold (mask ∘ unpool ∘ upsample) into MFMA A-frags (r1/r2-proven).
// ---------------------------------------------------------------------------
__global__ __launch_bounds__(256)
void prep_fold(const float* __restrict__ w,
               unsigned short* __restrict__ abf,
               float* __restrict__ wc0,
               float* __restrict__ wc2) {
    int tid = blockIdx.x * 256 + threadIdx.x;     // grid sized exactly
    int e = tid & 7;
    int l = (tid >> 3) & 63;
    int rest = tid >> 9;
    int d = rest % 3;
    int sd = rest / 3;
    int s = sd & 1;
    int eo = sd >> 1;
    int co = l & 15;
    int j = (l >> 4) * 8 + e;       // k index within eo's 32-wide window
    int slot = j >> 4, ci = j & 15;
    int r0 = (eo == 0) ? 0 : ((eo - 1) >> 1);
    int r1 = (eo == EDGES - 1) ? ((EDGES - 1) >> 1) : ((eo + 1) >> 1);
    int elo = (eo == 0) ? 0 : eo - 1;
    int ehi = (eo == EDGES - 1) ? EDGES - 1 : eo + 1;
    float W0 = 0.f, W1 = 0.f, W2 = 0.f;
    for (int ei = elo; ei <= ehi; ++ei) {
        int re = ei >> 1;
        bool take = slot ? (r1 != r0 && re == r1) : (re == r0);
        if (!take) continue;
        const float* wp = w + ((size_t)(eo * 16 + co) * COUT + (ei * 16 + ci)) * 3;
        W0 += wp[0]; W1 += wp[1]; W2 += wp[2];
    }
    // fold upsample: y[2m]=.25x[m-1]+.75x[m]; y[2m+1]=.75x[m]+.25x[m+1]
    float a;
    if (s == 0) {
        a = (d == 0) ? 0.75f * W0 + 0.25f * W1
          : (d == 1) ? 0.25f * W0 + 0.75f * W1 + 0.75f * W2
                     : 0.25f * W2;
    } else {
        a = (d == 0) ? 0.25f * W0
          : (d == 1) ? 0.75f * W0 + 0.75f * W1 + 0.25f * W2
                     : 0.25f * W1 + 0.75f * W2;
    }
    abf[tid] = f2bf(a);
    if (s == 0 && d == 0) {
        wc0[(eo * 16 + co) * 32 + j] = W0;
        wc2[(eo * 16 + co) * 32 + j] = W2;
    }
}

// ---------------------------------------------------------------------------
// Main: identical algebra to round-21 PASSING kernel; ONE variable: MT=512
// with 1024 threads, launch_bounds(1024,2) -> 2 blocks x 16 waves = still
// 32 waves/CU, still 64-VGPR budget, LDS 65.8 KB x2 = 131.6 <= 160 KB.
// Grid 1792 = 8 x 224 bijective XCD chunks (each XCD = 2 whole batches,
// same per-XCD L2 working set). Halves per-block fixed costs vs r21.
// ---------------------------------------------------------------------------
__global__ __launch_bounds__(1024, 2)
void skel_main(const float* __restrict__ x,
               const float* __restrict__ bias,
               const unsigned short* __restrict__ abf,
               const float* __restrict__ wc0,
               const float* __restrict__ wc2,
               float* __restrict__ out) {
    __shared__ __align__(16) unsigned short lds[ROWS * 64];
    // --- XCD swizzle: f -> (xcd = f&7) owns contiguous chunk of 224 ---
    const int f   = blockIdx.x;
    const int nf  = (f & 7) * 224 + (f >> 3);
    const int tb  = nf & 7;             // m-tile 0..7
    const int rst = nf >> 3;
    const int r   = rst % 14;           // region pair -> eo {2r, 2r+1}
    const int b   = rst / 14;           // batch 0..15
    const int t  = threadIdx.x;
    const int mstart = tb << 9;
    const int reg0 = (r == 0) ? 0 : r - 1;
    const int reg2 = (r == 13) ? 13 : r + 1;

    // ---- stage x -> LDS: 768 tasks (g 0..5, mq 0..127), single pass ----
    if (t < 768) {
        int g  = t >> 7;              // granule-column 0..5 (8 ch each)
        int mq = t & 127;             // row-quad: rows 1+4mq .. 4+4mq
        int rgb = g >> 1;             // region selector
        int reg = (rgb == 0) ? reg0 : ((rgb == 1) ? r : reg2);
        const float* xb = x + ((size_t)b * CIN + reg * 16 + (g & 1) * 8) * TIN
                          + mstart + 4 * mq;
        f32x4_t vf[8];
        #pragma unroll
        for (int i = 0; i < 8; ++i)
            vf[i] = *(const f32x4_t*)(xb + (size_t)i * TIN);
        #pragma unroll
        for (int q = 0; q < 4; ++q) {
            int qq = (q + mq) & 3;                // rotate rows across lanes
            int mr = 1 + 4 * mq + qq;             // 1..512
            i32x4_t u;
            #pragma unroll
            for (int j = 0; j < 4; ++j)
                u[j] = (int)((unsigned int)f2bf(vf[2 * j][qq]) |
                             ((unsigned int)f2bf(vf[2 * j + 1][qq]) << 16));
            int byte = (mr << 7) + (((g ^ (mr & 7))) << 4);
            *(i32x4_t*)((char*)lds + byte) = u;
        }
    }
    if (t < 96) {   // halo rows mr=0 (m-1) and mr=ROWS-1 (m+512), clamped
        int ch = (t < 48) ? t : t - 48;
        int rg = ch >> 4;
        int reg = (rg == 0) ? reg0 : ((rg == 1) ? r : reg2);
        int gch = reg * 16 + (ch & 15);
        int mr, m;
        if (t < 48) { mr = 0;        m = mstart - 1;  if (m < 0) m = 0; }
        else        { mr = ROWS - 1; m = mstart + MT; if (m > TIN - 1) m = TIN - 1; }
        float v = x[((size_t)b * CIN + gch) * TIN + m];
        *(unsigned short*)((char*)lds + lds_byte(mr, ch)) = f2bf(v);
    }

    const int l  = t & 63;
    const int wv = t >> 6;           // 0..15
    const int lc = l & 15;
    const int lg = l >> 4;

    __syncthreads();

    #pragma unroll
    for (int ei = 0; ei < 2; ++ei) {
        const int eo = 2 * r + ei;
        const int chb = 16 * ei;                      // eo's 32-ch window base
        // A-frags for this eo: [parity][d]
        bf16x8_t afr[2][3];
        #pragma unroll
        for (int s = 0; s < 2; ++s)
            #pragma unroll
            for (int d = 0; d < 3; ++d) {
                int4 tmp = *(const int4*)(abf + (size_t)(((eo * 2 + s) * 3 + d) * 64 + l) * 8);
                afr[s][d] = __builtin_bit_cast(bf16x8_t, tmp);
            }
        float bco[4];
        #pragma unroll
        for (int rr = 0; rr < 4; ++rr) bco[rr] = bias[eo * 16 + lg * 4 + rr];
        float* ob = out + ((size_t)b * COUT + eo * 16) * (size_t)T2V;

        #pragma unroll
        for (int tile = 0; tile < 2; ++tile) {
            int mloc = wv * 32 + tile * 16;
            f32x4_t acc0 = {0.f, 0.f, 0.f, 0.f};     // even t2
            f32x4_t acc1 = {0.f, 0.f, 0.f, 0.f};     // odd t2
            #pragma unroll
            for (int d = 0; d < 3; ++d) {
                int lmr = mloc + lc + d;
                int4 bd = *(const int4*)((char*)lds + lds_byte(lmr, chb + 8 * lg));
                bf16x8_t bfr = __builtin_bit_cast(bf16x8_t, bd);
                acc0 = __builtin_amdgcn_mfma_f32_16x16x32_bf16(afr[0][d], bfr, acc0, 0, 0, 0);
                acc1 = __builtin_amdgcn_mfma_f32_16x16x32_bf16(afr[1][d], bfr, acc1, 0, 0, 0);
            }
            int mcol = mstart + mloc + lc;
            // conv zero-pad corrections (before the shuffle so they propagate)
            if (tb == 0 && mloc == 0 && lc == 0) {                // t2 = 0
                #pragma unroll
                for (int rr = 0; rr < 4; ++rr) {
                    int co = lg * 4 + rr; float sum = 0.f;
                    for (int j = 0; j < 32; ++j)
                        sum += wc0[(eo * 16 + co) * 32 + j] *
                               bf2f(*(const unsigned short*)((char*)lds + lds_byte(1, chb + j)));
                    acc0[rr] -= sum;
                }
            }
            if (tb == (TIN / MT - 1) && mloc == MT - 16 && lc == 15) {   // t2 = 8191 (wv=15,tile=1)
                #pragma unroll
                for (int rr = 0; rr < 4; ++rr) {
                    int co = lg * 4 + rr; float sum = 0.f;
                    for (int j = 0; j < 32; ++j)
                        sum += wc2[(eo * 16 + co) * 32 + j] *
                               bf2f(*(const unsigned short*)((char*)lds + lds_byte(MT, chb + j)));
                    acc1[rr] -= sum;
                }
            }
            // epilogue: bias + LeakyReLU, lane-pair exchange, f32x4 NT store
            float ev[4], ov[4], xe[4], xo[4];
            #pragma unroll
            for (int rr = 0; rr < 4; ++rr) {
                float e = acc0[rr] + bco[rr];
                float o = acc1[rr] + bco[rr];
                ev[rr] = (e >= 0.f) ? e : 0.2f * e;
                ov[rr] = (o >= 0.f) ? o : 0.2f * o;
            }
            #pragma unroll
            for (int rr = 0; rr < 4; ++rr) {
                xe[rr] = __shfl_xor(ev[rr], 1);
                xo[rr] = __shfl_xor(ov[rr], 1);
            }
            if ((lc & 1) == 0) {
                #pragma unroll
                for (int rp = 0; rp < 2; ++rp) {
                    int rr = 2 * rp;                  // even lanes: rr 0, 2
                    f32x4_t pk = {ev[rr], ov[rr], xe[rr], xo[rr]};
                    __builtin_nontemporal_store(pk,
                        (f32x4_t*)(ob + (size_t)(lg * 4 + rr) * T2V + 2 * mcol));
                }
            } else {
                #pragma unroll
                for (int rp = 0; rp < 2; ++rp) {
                    int rr = 2 * rp + 1;              // odd lanes: rr 1, 3
                    f32x4_t pk = {xe[rr], xo[rr], ev[rr], ov[rr]};
                    __builtin_nontemporal_store(pk,
                        (f32x4_t*)(ob + (size_t)(lg * 4 + rr) * T2V + 2 * (mcol - 1)));
                }
            }
        }
    }
}

extern "C" void kernel_launch(void* const* d_in, const int* in_sizes, int n_in,
                              void* d_out, int out_size, void* d_ws, size_t ws_size,
                              hipStream_t stream) {
    const float* x    = (const float*)d_in[0];
    const float* w    = (const float*)d_in[1];
    const float* bias = (const float*)d_in[2];
    float* out = (float*)d_out;

    // workspace: abf 172032 B | wc0 57344 B | wc2 57344 B
    unsigned short* abf = (unsigned short*)d_ws;
    float* wc0 = (float*)((char*)d_ws + 172032);
    float* wc2 = (float*)((char*)d_ws + 172032 + 57344);

    prep_fold<<<336, 256, 0, stream>>>(w, abf, wc0, wc2);
    skel_main<<<1792, 1024, 0, stream>>>(x, bias, abf, wc0, wc2, out);
}

// Round 23
// 72.409 us; speedup vs baseline: 1.0946x; 1.0946x over previous
//
#include <hip/hip_runtime.h>

typedef __bf16 bf16x8_t __attribute__((ext_vector_type(8)));
typedef float  f32x4_t  __attribute__((ext_vector_type(4)));
typedef int    i32x4_t  __attribute__((ext_vector_type(4)));

#define EDGES 28
#define TIN   4096
#define T2V   8192
#define NB    16
#define CIN   224
#define COUT  448

__device__ __forceinline__ unsigned short f2bf(float f) {
    unsigned int u = __builtin_bit_cast(unsigned int, f);
    u = (u + 0x7fffu + ((u >> 16) & 1u)) >> 16;   // RNE
    return (unsigned short)u;
}
__device__ __forceinline__ float bf2f(unsigned short h) {
    unsigned int u = ((unsigned int)h) << 16;
    return __builtin_bit_cast(float, u);
}

// LDS layout: [mr][ch] rows of 128 B (48 ch used of 64), XOR-swizzled 16B slots.
__device__ __forceinline__ int lds_byte(int mr, int ch) {
    return (mr << 7) + ((((ch >> 3) ^ (mr & 7))) << 4) + ((ch & 7) << 1);
}

// ---------------------------------------------------------------------------
// Prep: fold (mask ∘ unpool ∘ upsample) into MFMA A-frags (r1/r2-proven).
// ---------------------------------------------------------------------------
__global__ __launch_bounds__(256)
void prep_fold(const float* __restrict__ w,
               unsigned short* __restrict__ abf,
               float* __restrict__ wc0,
               float* __restrict__ wc2) {
    int tid = blockIdx.x * 256 + threadIdx.x;     // grid sized exactly
    int e = tid & 7;
    int l = (tid >> 3) & 63;
    int rest = tid >> 9;
    int d = rest % 3;
    int sd = rest / 3;
    int s = sd & 1;
    int eo = sd >> 1;
    int co = l & 15;
    int j = (l >> 4) * 8 + e;       // k index within eo's 32-wide window
    int slot = j >> 4, ci = j & 15;
    int r0 = (eo == 0) ? 0 : ((eo - 1) >> 1);
    int r1 = (eo == EDGES - 1) ? ((EDGES - 1) >> 1) : ((eo + 1) >> 1);
    int elo = (eo == 0) ? 0 : eo - 1;
    int ehi = (eo == EDGES - 1) ? EDGES - 1 : eo + 1;
    float W0 = 0.f, W1 = 0.f, W2 = 0.f;
    for (int ei = elo; ei <= ehi; ++ei) {
        int re = ei >> 1;
        bool take = slot ? (r1 != r0 && re == r1) : (re == r0);
        if (!take) continue;
        const float* wp = w + ((size_t)(eo * 16 + co) * COUT + (ei * 16 + ci)) * 3;
        W0 += wp[0]; W1 += wp[1]; W2 += wp[2];
    }
    // fold upsample: y[2m]=.25x[m-1]+.75x[m]; y[2m+1]=.75x[m]+.25x[m+1]
    float a;
    if (s == 0) {
        a = (d == 0) ? 0.75f * W0 + 0.25f * W1
          : (d == 1) ? 0.25f * W0 + 0.75f * W1 + 0.75f * W2
                     : 0.25f * W2;
    } else {
        a = (d == 0) ? 0.25f * W0
          : (d == 1) ? 0.75f * W0 + 0.75f * W1 + 0.25f * W2
                     : 0.25f * W1 + 0.75f * W2;
    }
    abf[tid] = f2bf(a);
    if (s == 0 && d == 0) {
        wc0[(eo * 16 + co) * 32 + j] = W0;
        wc2[(eo * 16 + co) * 32 + j] = W2;
    }
}

// ---------------------------------------------------------------------------
// Main: round-21 PASSING kernel, resubmitted verbatim (best measured:
// 72.5 µs). XCD-bijective swizzle + MT=256 + 512 thr + launch_bounds(512,4)
// (= 4 blocks/CU x 8 waves = 32 waves/CU at 64-VGPR budget) + packed b128
// staging + MFMA + shfl-paired f32x4 NT stores.
// ---------------------------------------------------------------------------
__global__ __launch_bounds__(512, 4)
void skel_main(const float* __restrict__ x,
               const float* __restrict__ bias,
               const unsigned short* __restrict__ abf,
               const float* __restrict__ wc0,
               const float* __restrict__ wc2,
               float* __restrict__ out) {
    __shared__ __align__(16) unsigned short lds[258 * 64];
    // --- XCD swizzle: f -> (xcd = f&7) owns contiguous chunk of 448 ---
    const int f   = blockIdx.x;
    const int nf  = (f & 7) * 448 + (f >> 3);
    const int tb  = nf & 15;            // m-tile 0..15
    const int rst = nf >> 4;
    const int r   = rst % 14;           // region pair -> eo {2r, 2r+1}
    const int b   = rst / 14;           // batch 0..15
    const int t  = threadIdx.x;
    const int mstart = tb << 8;
    const int reg0 = (r == 0) ? 0 : r - 1;
    const int reg2 = (r == 13) ? 13 : r + 1;

    // ---- stage x -> LDS: 384 tasks (g, mq), single pass over 512 thr ----
    if (t < 384) {
        int g  = t >> 6;              // granule-column 0..5 (8 ch each)
        int mq = t & 63;              // row-quad: rows 1+4mq .. 4+4mq
        int rgb = g >> 1;             // region selector
        int reg = (rgb == 0) ? reg0 : ((rgb == 1) ? r : reg2);
        const float* xb = x + ((size_t)b * CIN + reg * 16 + (g & 1) * 8) * TIN
                          + mstart + 4 * mq;
        f32x4_t vf[8];
        #pragma unroll
        for (int i = 0; i < 8; ++i)
            vf[i] = *(const f32x4_t*)(xb + (size_t)i * TIN);
        #pragma unroll
        for (int q = 0; q < 4; ++q) {
            int qq = (q + mq) & 3;                // rotate rows across lanes
            int mr = 1 + 4 * mq + qq;             // 1..256
            i32x4_t u;
            #pragma unroll
            for (int j = 0; j < 4; ++j)
                u[j] = (int)((unsigned int)f2bf(vf[2 * j][qq]) |
                             ((unsigned int)f2bf(vf[2 * j + 1][qq]) << 16));
            int byte = (mr << 7) + (((g ^ (mr & 7))) << 4);
            *(i32x4_t*)((char*)lds + byte) = u;
        }
    }
    if (t < 96) {   // halo rows mr=0 (m-1) and mr=257 (m+256), clamped
        int ch = (t < 48) ? t : t - 48;
        int rg = ch >> 4;
        int reg = (rg == 0) ? reg0 : ((rg == 1) ? r : reg2);
        int gch = reg * 16 + (ch & 15);
        int mr, m;
        if (t < 48) { mr = 0;   m = mstart - 1;   if (m < 0) m = 0; }
        else        { mr = 257; m = mstart + 256; if (m > TIN - 1) m = TIN - 1; }
        float v = x[((size_t)b * CIN + gch) * TIN + m];
        *(unsigned short*)((char*)lds + lds_byte(mr, ch)) = f2bf(v);
    }

    const int l  = t & 63;
    const int wv = t >> 6;           // 0..7
    const int lc = l & 15;
    const int lg = l >> 4;

    __syncthreads();

    #pragma unroll
    for (int ei = 0; ei < 2; ++ei) {
        const int eo = 2 * r + ei;
        const int chb = 16 * ei;                      // eo's 32-ch window base
        // A-frags for this eo: [parity][d]
        bf16x8_t afr[2][3];
        #pragma unroll
        for (int s = 0; s < 2; ++s)
            #pragma unroll
            for (int d = 0; d < 3; ++d) {
                int4 tmp = *(const int4*)(abf + (size_t)(((eo * 2 + s) * 3 + d) * 64 + l) * 8);
                afr[s][d] = __builtin_bit_cast(bf16x8_t, tmp);
            }
        float bco[4];
        #pragma unroll
        for (int rr = 0; rr < 4; ++rr) bco[rr] = bias[eo * 16 + lg * 4 + rr];
        float* ob = out + ((size_t)b * COUT + eo * 16) * (size_t)T2V;

        #pragma unroll
        for (int tile = 0; tile < 2; ++tile) {
            int mloc = wv * 32 + tile * 16;
            f32x4_t acc0 = {0.f, 0.f, 0.f, 0.f};     // even t2
            f32x4_t acc1 = {0.f, 0.f, 0.f, 0.f};     // odd t2
            #pragma unroll
            for (int d = 0; d < 3; ++d) {
                int lmr = mloc + lc + d;
                int4 bd = *(const int4*)((char*)lds + lds_byte(lmr, chb + 8 * lg));
                bf16x8_t bfr = __builtin_bit_cast(bf16x8_t, bd);
                acc0 = __builtin_amdgcn_mfma_f32_16x16x32_bf16(afr[0][d], bfr, acc0, 0, 0, 0);
                acc1 = __builtin_amdgcn_mfma_f32_16x16x32_bf16(afr[1][d], bfr, acc1, 0, 0, 0);
            }
            int mcol = mstart + mloc + lc;
            // conv zero-pad corrections (before the shuffle so they propagate)
            if (tb == 0 && mloc == 0 && lc == 0) {                // t2 = 0
                #pragma unroll
                for (int rr = 0; rr < 4; ++rr) {
                    int co = lg * 4 + rr; float sum = 0.f;
                    for (int j = 0; j < 32; ++j)
                        sum += wc0[(eo * 16 + co) * 32 + j] *
                               bf2f(*(const unsigned short*)((char*)lds + lds_byte(1, chb + j)));
                    acc0[rr] -= sum;
                }
            }
            if (tb == (TIN / 256 - 1) && mloc == 240 && lc == 15) {   // t2 = 8191 (wv=7,tile=1)
                #pragma unroll
                for (int rr = 0; rr < 4; ++rr) {
                    int co = lg * 4 + rr; float sum = 0.f;
                    for (int j = 0; j < 32; ++j)
                        sum += wc2[(eo * 16 + co) * 32 + j] *
                               bf2f(*(const unsigned short*)((char*)lds + lds_byte(256, chb + j)));
                    acc1[rr] -= sum;
                }
            }
            // epilogue: bias + LeakyReLU, lane-pair exchange, f32x4 NT store
            float ev[4], ov[4], xe[4], xo[4];
            #pragma unroll
            for (int rr = 0; rr < 4; ++rr) {
                float e = acc0[rr] + bco[rr];
                float o = acc1[rr] + bco[rr];
                ev[rr] = (e >= 0.f) ? e : 0.2f * e;
                ov[rr] = (o >= 0.f) ? o : 0.2f * o;
            }
            #pragma unroll
            for (int rr = 0; rr < 4; ++rr) {
                xe[rr] = __shfl_xor(ev[rr], 1);
                xo[rr] = __shfl_xor(ov[rr], 1);
            }
            if ((lc & 1) == 0) {
                #pragma unroll
                for (int rp = 0; rp < 2; ++rp) {
                    int rr = 2 * rp;                  // even lanes: rr 0, 2
                    f32x4_t pk = {ev[rr], ov[rr], xe[rr], xo[rr]};
                    __builtin_nontemporal_store(pk,
                        (f32x4_t*)(ob + (size_t)(lg * 4 + rr) * T2V + 2 * mcol));
                }
            } else {
                #pragma unroll
                for (int rp = 0; rp < 2; ++rp) {
                    int rr = 2 * rp + 1;              // odd lanes: rr 1, 3
                    f32x4_t pk = {xe[rr], xo[rr], ev[rr], ov[rr]};
                    __builtin_nontemporal_store(pk,
                        (f32x4_t*)(ob + (size_t)(lg * 4 + rr) * T2V + 2 * (mcol - 1)));
                }
            }
        }
    }
}

extern "C" void kernel_launch(void* const* d_in, const int* in_sizes, int n_in,
                              void* d_out, int out_size, void* d_ws, size_t ws_size,
                              hipStream_t stream) {
    const float* x    = (const float*)d_in[0];
    const float* w    = (const float*)d_in[1];
    const float* bias = (const float*)d_in[2];
    float* out = (float*)d_out;

    // workspace: abf 172032 B | wc0 57344 B | wc2 57344 B
    unsigned short* abf = (unsigned short*)d_ws;
    float* wc0 = (float*)((char*)d_ws + 172032);
    float* wc2 = (float*)((char*)d_ws + 172032 + 57344);

    prep_fold<<<336, 256, 0, stream>>>(w, abf, wc0, wc2);
    skel_main<<<3584, 512, 0, stream>>>(x, bias, abf, wc0, wc2, out);
}